// Round 1
// 1231.541 us; speedup vs baseline: 1.6314x; 1.6314x over previous
//
#include <hip/hip_runtime.h>
#include <hip/hip_bf16.h>
#include <stdint.h>

typedef unsigned short ushort_t;
typedef ushort_t u16x8 __attribute__((ext_vector_type(8)));
typedef __bf16 bf16x8 __attribute__((ext_vector_type(8)));
typedef float f32x4 __attribute__((ext_vector_type(4)));

union S8B { u16x8 s; bf16x8 b; };

#define NGRAPH 64

// fp32 -> bf16 round-to-nearest-even, manual bit math (no dtype surprises)
__device__ __forceinline__ ushort_t f2b(float f) {
    union { float f; unsigned u; } v; v.f = f;
    unsigned r = v.u + 0x7FFFu + ((v.u >> 16) & 1u);
    return (ushort_t)(r >> 16);
}

// ---------------------------------------------------------------------------
// Fused attention-pool kernel: per 128-row tile
//   H = relu(X@W1 + b1)   (scores via bf16 MFMA, fp32 acc; X,W fp32 in HBM)
//   s = H@W2 + b2 ; e = exp(s)        (softmax without max-shift: |s| small)
//   sum_ex[seg][f] += e * x[row][f] (fp32 re-read; LLC-hot) ; den[seg] += e
//   Accumulation: wave w owns rows [32w,32w+32), lane l owns features
//   [4l,4l+4) (float4). 8-deep load batching so 8 float4 loads are in
//   flight before the branchy seg-check/FMA consume loop.
// ---------------------------------------------------------------------------
__global__ __launch_bounds__(256, 2)
void pool_kernel(const float* __restrict__ Xg, int nrows,
                 const int* __restrict__ rowmap,   // null => identity
                 const int* __restrict__ segarr,   // seg per ORIGINAL row index
                 const float* __restrict__ W1, const float* __restrict__ b1,
                 const float* __restrict__ W2, const float* __restrict__ b2,
                 float* __restrict__ sumex,        // [64][768] combined layout
                 float* __restrict__ den,          // [64] for this set
                 int set)
{
    __shared__ S8B   sX[16 * 64];     // 16KB: 2 k-steps x 8 m-tiles, frag-linear
    __shared__ float sbuf[4][128];    // per-wave partial scores
    __shared__ float4 esbuf[128];     // (e, seg-bits, rowg-bits, 0)

    const int tid = threadIdx.x;
    const int w = tid >> 6, l = tid & 63;
    const int c = l & 15, q = l >> 4;

    // ---- W1 B-fragments in registers (wave w owns cols [w*32, w*32+32))
    bf16x8 bfr[8][2];
    float b1v[2], w2v[2];
#pragma unroll
    for (int ct = 0; ct < 2; ++ct) {
        const int n = w * 32 + ct * 16 + c;
        b1v[ct] = b1[n];
        w2v[ct] = W2[n];
#pragma unroll
        for (int ks = 0; ks < 8; ++ks) {
            S8B tmp;
#pragma unroll
            for (int j = 0; j < 8; ++j)
                tmp.s[j] = f2b(W1[(ks * 32 + q * 8 + j) * 128 + n]);
            bfr[ks][ct] = tmp.b;
        }
    }
    const float b2f = b2[0];

    const int ntiles = (nrows + 127) >> 7;
    const int tpb = (ntiles + gridDim.x - 1) / gridDim.x;
    const int tile0 = blockIdx.x * tpb;
    const int tile1 = min(tile0 + tpb, ntiles);

    // per-wave running accumulation state (uniform within a wave)
    float ac0 = 0.f, ac1 = 0.f, ac2 = 0.f, ac3 = 0.f;  // features 4l..4l+3
    float dacc = 0.f;                                   // lane 0: denom
    int seg_cur = -1;

    for (int tile = tile0; tile < tile1; ++tile) {
        const int row0 = tile << 7;

        f32x4 acc[8][2];
#pragma unroll
        for (int mt = 0; mt < 8; ++mt) {
            acc[mt][0] = f32x4{0.f, 0.f, 0.f, 0.f};
            acc[mt][1] = f32x4{0.f, 0.f, 0.f, 0.f};
        }

        // ---- per-tile source addresses for staging (row fixed across kc)
        const float* srcI[4];
#pragma unroll
        for (int i = 0; i < 4; ++i) {
            const int ii = w * 4 + i;
            const int ks2 = ii >> 3, mt = ii & 7;
            int p = row0 + mt * 16 + c;
            if (p > nrows - 1) p = nrows - 1;
            const int rowg = rowmap ? rowmap[p] : p;
            srcI[i] = Xg + (size_t)rowg * 256 + ks2 * 32 + q * 8;
        }

        // ---- prologue: load kc=0 chunk into registers
        float4 Alo[4], Ahi[4];
#pragma unroll
        for (int i = 0; i < 4; ++i) {
            Alo[i] = *(const float4*)(srcI[i]);
            Ahi[i] = *(const float4*)(srcI[i] + 4);
        }

#pragma unroll
        for (int kc = 0; kc < 4; ++kc) {
            // stage current chunk (fp32->bf16, frag-linear)
#pragma unroll
            for (int i = 0; i < 4; ++i) {
                const int ii = w * 4 + i;
                S8B t8;
                t8.s[0] = f2b(Alo[i].x); t8.s[1] = f2b(Alo[i].y);
                t8.s[2] = f2b(Alo[i].z); t8.s[3] = f2b(Alo[i].w);
                t8.s[4] = f2b(Ahi[i].x); t8.s[5] = f2b(Ahi[i].y);
                t8.s[6] = f2b(Ahi[i].z); t8.s[7] = f2b(Ahi[i].w);
                sX[ii * 64 + l] = t8;
            }
            __syncthreads();
            // issue next chunk's loads; they complete under the MFMAs below
            if (kc < 3) {
#pragma unroll
                for (int i = 0; i < 4; ++i) {
                    const float* src = srcI[i] + (kc + 1) * 64;
                    Alo[i] = *(const float4*)(src);
                    Ahi[i] = *(const float4*)(src + 4);
                }
            }
#pragma unroll
            for (int ks2 = 0; ks2 < 2; ++ks2) {
                const int ks = 2 * kc + ks2;
#pragma unroll
                for (int mt = 0; mt < 8; ++mt) {
                    bf16x8 a = sX[(ks2 * 8 + mt) * 64 + l].b;
                    acc[mt][0] = __builtin_amdgcn_mfma_f32_16x16x32_bf16(a, bfr[ks][0], acc[mt][0], 0, 0, 0);
                    acc[mt][1] = __builtin_amdgcn_mfma_f32_16x16x32_bf16(a, bfr[ks][1], acc[mt][1], 0, 0, 0);
                }
            }
            __syncthreads();
        }

        // ---- epilogue: s partials. C/D layout: col=lane&15, row=quad*4+r
#pragma unroll
        for (int mt = 0; mt < 8; ++mt) {
            float pr[4];
#pragma unroll
            for (int r = 0; r < 4; ++r)
                pr[r] = fmaxf(acc[mt][0][r] + b1v[0], 0.f) * w2v[0]
                      + fmaxf(acc[mt][1][r] + b1v[1], 0.f) * w2v[1];
#pragma unroll
            for (int off = 1; off < 16; off <<= 1) {
#pragma unroll
                for (int r = 0; r < 4; ++r)
                    pr[r] += __shfl_xor(pr[r], off);
            }
            if (c == 0) {
#pragma unroll
                for (int r = 0; r < 4; ++r)
                    sbuf[w][mt * 16 + q * 4 + r] = pr[r];
            }
        }
        __syncthreads();

        // ---- e = exp(s), plus seg/rowg, broadcast via LDS
        if (tid < 128) {
            float s = sbuf[0][tid] + sbuf[1][tid] + sbuf[2][tid] + sbuf[3][tid] + b2f;
            s = fminf(fmaxf(s, -60.f), 60.f);   // inf insurance; never hits for sane data
            const int p = row0 + tid;
            float e = 0.f; int seg = 0; int rowg = 0;
            if (p < nrows) {
                rowg = rowmap ? rowmap[p] : p;
                seg = segarr[rowg];
                e = expf(s);
            }
            esbuf[tid] = make_float4(e, __int_as_float(seg), __int_as_float(rowg), 0.f);
        }
        __syncthreads();

        // ---- weighted accumulation: wave w owns rows [32w,32w+32), lane l
        // owns features [4l,4l+4). Loads batched 8-deep so they pipeline;
        // seg-check/flush runs after all 8 are in flight. X re-read is
        // LLC-hot (staged moments ago).
        const int rbase = w * 32;
#pragma unroll 1
        for (int c8 = 0; c8 < 4; ++c8) {
            float4 xv[8]; float ev[8]; int sv[8];
#pragma unroll
            for (int j = 0; j < 8; ++j) {
                const float4 es = esbuf[rbase + c8 * 8 + j];
                ev[j] = es.x;
                sv[j] = __float_as_int(es.y);
                const int rowg = __float_as_int(es.z);
                xv[j] = *(const float4*)(Xg + (size_t)rowg * 256 + 4 * l);
            }
#pragma unroll
            for (int j = 0; j < 8; ++j) {
                if (ev[j] > 0.f) {           // uniform; false only for tail padding
                    if (sv[j] != seg_cur) {  // uniform within wave
                        if (seg_cur >= 0) {
                            float* dst = &sumex[seg_cur * 768 + set * 256 + 4 * l];
                            unsafeAtomicAdd(dst + 0, ac0);
                            unsafeAtomicAdd(dst + 1, ac1);
                            unsafeAtomicAdd(dst + 2, ac2);
                            unsafeAtomicAdd(dst + 3, ac3);
                            ac0 = ac1 = ac2 = ac3 = 0.f;
                            if (l == 0) { unsafeAtomicAdd(&den[seg_cur], dacc); dacc = 0.f; }
                        }
                        seg_cur = sv[j];
                    }
                    ac0 += ev[j] * xv[j].x;
                    ac1 += ev[j] * xv[j].y;
                    ac2 += ev[j] * xv[j].z;
                    ac3 += ev[j] * xv[j].w;
                    if (l == 0) dacc += ev[j];
                }
            }
        }
        // no end-of-tile barrier needed: next tile's first touch of shared
        // state (sX write) is never read before the post-staging barrier,
        // and esbuf/sbuf are rewritten only after further barriers.
    }

    if (seg_cur >= 0) {
        float* dst = &sumex[seg_cur * 768 + set * 256 + 4 * l];
        unsafeAtomicAdd(dst + 0, ac0);
        unsafeAtomicAdd(dst + 1, ac1);
        unsafeAtomicAdd(dst + 2, ac2);
        unsafeAtomicAdd(dst + 3, ac3);
        if (l == 0) unsafeAtomicAdd(&den[seg_cur], dacc);
    }
}

// ---------------------------------------------------------------------------
// Cross-edge bucket sort by segment (order within segment irrelevant)
// ---------------------------------------------------------------------------
__global__ void k_zero(unsigned int* p, int n) {
    const int i = blockIdx.x * 256 + threadIdx.x;
    if (i < n) p[i] = 0u;
}

__global__ void k_hist(const int* __restrict__ ci0, const int* __restrict__ lb,
                       int* __restrict__ segc, unsigned* __restrict__ hist, int n) {
    __shared__ unsigned cnt[NGRAPH];
    if (threadIdx.x < NGRAPH) cnt[threadIdx.x] = 0u;
    __syncthreads();
    for (int i = blockIdx.x * blockDim.x + threadIdx.x; i < n; i += gridDim.x * blockDim.x) {
        const int s = lb[ci0[i]];
        segc[i] = s;
        atomicAdd(&cnt[s], 1u);
    }
    __syncthreads();
    if (threadIdx.x < NGRAPH && cnt[threadIdx.x]) atomicAdd(&hist[threadIdx.x], cnt[threadIdx.x]);
}

__global__ void k_scan(const unsigned* __restrict__ hist, unsigned* __restrict__ counter) {
    __shared__ unsigned h[NGRAPH];
    const int t = threadIdx.x;           // 64 threads
    h[t] = hist[t];
    __syncthreads();
    unsigned acc = 0;
    for (int i = 0; i < t; ++i) acc += h[i];
    counter[t] = acc;
}

__global__ void k_scatter(const int* __restrict__ segc, unsigned* __restrict__ counter,
                          int* __restrict__ sorted, int n) {
    __shared__ unsigned cnt[NGRAPH], cnt2[NGRAPH], gbase[NGRAPH];
    const int per = (n + gridDim.x - 1) / gridDim.x;
    const int lo = blockIdx.x * per;
    const int hi = min(lo + per, n);
    if (threadIdx.x < NGRAPH) { cnt[threadIdx.x] = 0u; cnt2[threadIdx.x] = 0u; }
    __syncthreads();
    for (int i = lo + threadIdx.x; i < hi; i += blockDim.x) atomicAdd(&cnt[segc[i]], 1u);
    __syncthreads();
    if (threadIdx.x < NGRAPH && cnt[threadIdx.x])
        gbase[threadIdx.x] = atomicAdd(&counter[threadIdx.x], cnt[threadIdx.x]);
    __syncthreads();
    for (int i = lo + threadIdx.x; i < hi; i += blockDim.x) {
        const int s = segc[i];
        const unsigned r = atomicAdd(&cnt2[s], 1u);
        sorted[gbase[s] + r] = i;
    }
}

// ---------------------------------------------------------------------------
// Final MLP on [64, 768] combined (normalization folded in): tiny, all fp32.
// ---------------------------------------------------------------------------
__global__ __launch_bounds__(256)
void k_mlp(const float* __restrict__ sumex, const float* __restrict__ den,
           const float* __restrict__ W1, const float* __restrict__ bb1,
           const float* __restrict__ W2, const float* __restrict__ bb2,
           const float* __restrict__ oW, const float* __restrict__ ob,
           float* __restrict__ out)
{
    __shared__ float comb[768];
    __shared__ float h1[256];
    __shared__ float h2[128];
    const int g = blockIdx.x, t = threadIdx.x;

    for (int i = t; i < 768; i += 256) {
        const float d = den[(i >> 8) * NGRAPH + g];
        comb[i] = (d > 0.f) ? sumex[g * 768 + i] / d : 0.f;
    }
    __syncthreads();
    {
        float a = bb1[t];
        for (int k = 0; k < 768; ++k) a += comb[k] * W1[k * 256 + t];
        h1[t] = fmaxf(a, 0.f);
    }
    __syncthreads();
    if (t < 128) {
        float a = bb2[t];
        for (int k = 0; k < 256; ++k) a += h1[k] * W2[k * 128 + t];
        h2[t] = fmaxf(a, 0.f);
    }
    __syncthreads();
    if (t < 64) {
        float v = h2[t] * oW[t] + h2[t + 64] * oW[t + 64];
        for (int off = 32; off; off >>= 1) v += __shfl_xor(v, off);
        if (t == 0) out[g] = v + ob[0];
    }
}

// ---------------------------------------------------------------------------
extern "C" void kernel_launch(void* const* d_in, const int* in_sizes, int n_in,
                              void* d_out, int out_size, void* d_ws, size_t ws_size,
                              hipStream_t stream) {
    (void)n_in; (void)out_size; (void)ws_size;

    const float* rec = (const float*)d_in[0];
    const float* lig = (const float*)d_in[1];
    const float* cro = (const float*)d_in[2];
    const int* cross_idx0 = (const int*)d_in[3];   // row 0 of [2, N_CROSS]
    const int* pbatch = (const int*)d_in[4];
    const int* lbatch = (const int*)d_in[5];
    // d_in[6] = num_graphs (64)
    const float* paW1 = (const float*)d_in[7];
    const float* pab1 = (const float*)d_in[8];
    const float* paW2 = (const float*)d_in[9];
    const float* pab2 = (const float*)d_in[10];
    const float* laW1 = (const float*)d_in[11];
    const float* lab1 = (const float*)d_in[12];
    const float* laW2 = (const float*)d_in[13];
    const float* lab2 = (const float*)d_in[14];
    const float* caW1 = (const float*)d_in[15];
    const float* cab1 = (const float*)d_in[16];
    const float* caW2 = (const float*)d_in[17];
    const float* cab2 = (const float*)d_in[18];
    const float* mW1 = (const float*)d_in[19];
    const float* mb1 = (const float*)d_in[20];
    const float* mW2 = (const float*)d_in[21];
    const float* mb2 = (const float*)d_in[22];
    const float* oW  = (const float*)d_in[23];
    const float* ob  = (const float*)d_in[24];

    const int NP = in_sizes[0] / 256;
    const int NL = in_sizes[1] / 256;
    const int NC = in_sizes[2] / 256;

    // workspace layout (words)
    float* ws = (float*)d_ws;
    float* sumex = ws;                                   // 64*768
    float* den = ws + 64 * 768;                          // 3*64 (192)
    unsigned* hist = (unsigned*)(ws + 64 * 768 + 192);   // 64
    unsigned* counter = hist + 64;                       // 64
    int* segc = (int*)(counter + 64);                    // NC
    int* sorted = segc + NC;                             // NC

    const int zero_words = 64 * 768 + 192 + 128;
    k_zero<<<dim3((zero_words + 255) / 256), dim3(256), 0, stream>>>((unsigned*)d_ws, zero_words);

    k_hist<<<dim3(512), dim3(256), 0, stream>>>(cross_idx0, lbatch, segc, hist, NC);
    k_scan<<<dim3(1), dim3(64), 0, stream>>>(hist, counter);
    k_scatter<<<dim3(512), dim3(256), 0, stream>>>(segc, counter, sorted, NC);

    pool_kernel<<<dim3(512), dim3(256), 0, stream>>>(rec, NP, (const int*)nullptr, pbatch,
                                                     paW1, pab1, paW2, pab2, sumex, den + 0, 0);
    pool_kernel<<<dim3(512), dim3(256), 0, stream>>>(lig, NL, (const int*)nullptr, lbatch,
                                                     laW1, lab1, laW2, lab2, sumex, den + 64, 1);
    pool_kernel<<<dim3(512), dim3(256), 0, stream>>>(cro, NC, sorted, segc,
                                                     caW1, cab1, caW2, cab2, sumex, den + 128, 2);

    k_mlp<<<dim3(64), dim3(256), 0, stream>>>(sumex, den, mW1, mb1, mW2, mb2, oW, ob,
                                              (float*)d_out);
}